// Round 1
// baseline (27.414 us; speedup 1.0000x reference)
//
#include <hip/hip_runtime.h>

// Bspline control-grid -> dense flow field
// inputs: [B=16, T=25, 2*32*32] fp32  -> reshaped [N=400, 32, 32, 2]
// output: [16, 25, 192, 192, 2] fp32 = -192 * bilinear_upsample(grid)

#define GDIM 32
#define HOUT 192
#define WOUT 192
#define NIMG 400
#define ROWS_PER_BLOCK 24
#define BLOCKS_PER_IMG (HOUT / ROWS_PER_BLOCK)   // 8
#define THREADS 256
// per block: ROWS_PER_BLOCK * (WOUT/2) = 24*96 = 2304 float4 units -> 9 iters
#define ITERS ((ROWS_PER_BLOCK * (WOUT / 2)) / THREADS)

__global__ __launch_bounds__(THREADS) void bspline_flow_kernel(
    const float* __restrict__ in, float* __restrict__ out) {
  __shared__ float2 cgrid[GDIM * GDIM];  // 8 KB

  const int blk   = blockIdx.x;
  const int n     = blk / BLOCKS_PER_IMG;
  const int chunk = blk % BLOCKS_PER_IMG;
  const int tid   = threadIdx.x;

  // Stage this image's 32x32x2 control grid into LDS (coalesced float4).
  {
    const float4* src = reinterpret_cast<const float4*>(in + (size_t)n * (2 * GDIM * GDIM));
    float4* dst = reinterpret_cast<float4*>(cgrid);
    dst[tid]       = src[tid];          // 2048 floats = 512 float4
    dst[tid + 256] = src[tid + 256];
  }
  __syncthreads();

  const int row0 = chunk * ROWS_PER_BLOCK;
  const float qscale = 31.0f / 192.0f;  // (size_in-1)/limit
  const float oscale = -192.0f;         // -H == -W

  float4* outv = reinterpret_cast<float4*>(out + (size_t)n * (HOUT * WOUT * 2));

#pragma unroll
  for (int it = 0; it < ITERS; ++it) {
    const int t  = tid + it * THREADS;
    const int yl = t / (WOUT / 2);          // local row 0..23
    const int xp = t - yl * (WOUT / 2);     // x-pair index 0..95
    const int y  = row0 + yl;
    const int x0pix = xp * 2;

    // y-axis interp coords (shared by both pixels)
    const float qy = (float)y * qscale;
    const float fy = floorf(qy);
    const int   y0 = (int)fy;               // <= 30 always
    const float ay = qy - fy;
    const float by = 1.0f - ay;

    const float2* rowA = &cgrid[y0 * GDIM];
    const float2* rowB = &cgrid[(y0 + 1) * GDIM];

    float res[4];
#pragma unroll
    for (int k = 0; k < 2; ++k) {
      const int   x  = x0pix + k;
      const float qx = (float)x * qscale;
      const float fx = floorf(qx);
      const int   x0 = (int)fx;              // <= 30 always
      const float ax = qx - fx;
      const float bx = 1.0f - ax;

      const float2 p00 = rowA[x0];
      const float2 p01 = rowA[x0 + 1];
      const float2 p10 = rowB[x0];
      const float2 p11 = rowB[x0 + 1];

      // rows over y, then cols over x (matches reference order)
      const float py0x = p00.x * by + p10.x * ay;
      const float py0y = p00.y * by + p10.y * ay;
      const float py1x = p01.x * by + p11.x * ay;
      const float py1y = p01.y * by + p11.y * ay;

      res[2 * k + 0] = (py0x * bx + py1x * ax) * oscale;
      res[2 * k + 1] = (py0y * bx + py1y * ax) * oscale;
    }

    // out element index = (y*W + x0pix)*2 floats -> float4 index y*96 + xp
    outv[(size_t)y * (WOUT / 2) + xp] = make_float4(res[0], res[1], res[2], res[3]);
  }
}

extern "C" void kernel_launch(void* const* d_in, const int* in_sizes, int n_in,
                              void* d_out, int out_size, void* d_ws, size_t ws_size,
                              hipStream_t stream) {
  const float* in = (const float*)d_in[0];
  float* out = (float*)d_out;
  dim3 grid(NIMG * BLOCKS_PER_IMG);
  bspline_flow_kernel<<<grid, THREADS, 0, stream>>>(in, out);
}